// Round 8
// baseline (194.084 us; speedup 1.0000x reference)
//
#include <hip/hip_runtime.h>
#include <math.h>

#define WW 1024
#define HH 1024
#define TI 64          // output tile extent in i (x)
#define TJ 128         // output tile extent in j (y)
#define HALO_J 148     // hc (y) extent = TJ + 20
#define VALID_I 84     // valid hr extent for fallback fused kernel
#define FILL_I 96      // fallback fill extent
#define PITCH_T 104    // ThT row pitch in elems; 208B, 52 dwords == 20 mod 32 (conflict-free)
#define AOFF 448       // float offset of A-pattern table (origin i0-10, fallback)
#define AOFF2 21952    // float offset of shifted A-pattern table (origin i0-16, split path)
#define YOFF 43520     // float offset of bf16 warped image (32MB)
#define NEED_WS (174080u + 33554432u)

typedef short short8 __attribute__((ext_vector_type(8)));
typedef float float16 __attribute__((ext_vector_type(16)));

__device__ __forceinline__ unsigned short f2bf(float f) {
    union { float f; unsigned int u; } c; c.f = f;
    unsigned int u = c.u;
    return (unsigned short)((u + 0x7FFFu + ((u >> 16) & 1u)) >> 16);
}

// warped-image sample at integer grid (I, J); val=0 outside image (conv zero-pad)
__device__ __forceinline__ float warp_sample(const float* __restrict__ sb, int I, int J,
                                             float bpar, float rc2, float sub0, float sub1,
                                             float x0, float y0) {
    const float SSTEP = 2.0f / 1023.0f;
    float yv = fmaf((float)J, SSTEP, -1.0f);
    float xv = fmaf((float)I, SSTEP, -1.0f);
    float dx = xv - x0;
    float dy = yv - y0;
    float s = bpar * __builtin_amdgcn_rsqf(dx * dx + dy * dy + rc2);
    float gx = xv - dx * s + sub0;
    float gy = yv - dy * s + sub1;
    float ix = (gx + 1.0f) * (0.5f * 1023.0f);
    float iy = (gy + 1.0f) * (0.5f * 1023.0f);
    float fx = floorf(ix), fy = floorf(iy);
    float wx1 = ix - fx, wy1 = iy - fy;
    float wx0 = 1.f - wx1, wy0 = 1.f - wy1;
    int xi0 = (int)fx, yi0 = (int)fy;
    int xi1 = xi0 + 1, yi1 = yi0 + 1;
    int xc0 = min(max(xi0, 0), WW - 1);
    int xc1 = min(max(xi1, 0), WW - 1);
    int yc0 = min(max(yi0, 0), HH - 1);
    int yc1 = min(max(yi1, 0), HH - 1);
    bool vx0 = (unsigned)xi0 < WW, vx1 = (unsigned)xi1 < WW;
    bool vy0 = (unsigned)yi0 < HH, vy1 = (unsigned)yi1 < HH;
    float w00 = (vx0 && vy0) ? wy0 * wx0 : 0.f;
    float w01 = (vx1 && vy0) ? wy0 * wx1 : 0.f;
    float w10 = (vx0 && vy1) ? wy1 * wx0 : 0.f;
    float w11 = (vx1 && vy1) ? wy1 * wx1 : 0.f;
    float v00 = sb[yc0 * WW + xc0];
    float v01 = sb[yc0 * WW + xc1];
    float v10 = sb[yc1 * WW + xc0];
    float v11 = sb[yc1 * WW + xc1];
    return v00 * w00 + v01 * w01 + v10 * w10 + v11 * w11;
}

// ---------------- prep: PSF normalize, params, both Toeplitz A-pattern tables
__global__ void prep_kernel(const float* __restrict__ raw_psf,
                            const float* __restrict__ x0p, const float* __restrict__ y0p,
                            const float* __restrict__ raw_b, const float* __restrict__ raw_rc,
                            const float* __restrict__ raw_sub,
                            float* __restrict__ ws) {
    __shared__ float red[512];
    __shared__ float psn[441];
    int t = threadIdx.x;
    float v = 0.f;
    if (t < 441) v = fmaxf(raw_psf[t], 0.f);
    red[t] = v;
    __syncthreads();
    for (int s = 256; s > 0; s >>= 1) {
        if (t < s) red[t] += red[t + s];
        __syncthreads();
    }
    float sum = fmaxf(red[0], 1e-12f);
    if (t < 441) { float pn = v / sum; ws[t] = pn; psn[t] = pn; }
    if (t == 0) {
        float b  = log1pf(expf(raw_b[0]))  + 1e-8f;
        float rc = log1pf(expf(raw_rc[0])) + 1e-8f;
        ws[441] = b;
        ws[442] = 1e-12f + rc * rc;
        ws[443] = 0.25f * tanhf(raw_sub[0]);
        ws[444] = 0.25f * tanhf(raw_sub[1]);
        ws[445] = x0p[0];
        ws[446] = y0p[0];
    }
    __syncthreads();

    short* A  = (short*)(ws + AOFF);
    short* A2 = (short*)(ws + AOFF2);
    for (int g = t; g < 21 * 256; g += 512) {      // g = v*256 + d*64 + l
        int vv = g >> 8;
        int r  = g & 255;
        int d  = r >> 6;
        int l  = r & 63;
        int m  = l & 31;
        int k0 = (l >> 5) << 3;
        short8 o8, o8b;
#pragma unroll
        for (int q = 0; q < 8; ++q) {
            int u = 16 * d + k0 + q - m;
            unsigned short pv = 0, pv2 = 0;
            if ((unsigned)u <= 20u) pv = f2bf(psn[u * 21 + vv]);
            int u2 = u - 6;
            if ((unsigned)u2 <= 20u) pv2 = f2bf(psn[u2 * 21 + vv]);
            o8[q]  = (short)pv;
            o8b[q] = (short)pv2;
        }
        *(short8*)&A[(size_t)g * 8]  = o8;
        *(short8*)&A2[(size_t)g * 8] = o8b;
    }
}

// ---------------- split kernel 1: warp each pixel EXACTLY ONCE -> bf16 image --
// 2-row pipelined gather: 32 independent loads held live by sched_barrier(0)
// so exposed HBM latency is paid once per 2 rows, not once per quad.
__global__ __launch_bounds__(256, 4) void warp_kernel(
        const float* __restrict__ src, const float* __restrict__ pp,
        unsigned short* __restrict__ yw) {
    const float bpar = pp[441], rc2 = pp[442];
    const float sub0 = pp[443], sub1 = pp[444];
    const float x0 = pp[445], y0 = pp[446];
    const float SSTEP = 2.0f / 1023.0f;

    const int tid = threadIdx.x;
    const int nb  = blockIdx.x;            // 2048 blocks = 16 images x 128
    const int b0  = nb >> 7;
    const int J0  = (nb & 127) << 3;       // 8 rows per block
    const float* sb = src + ((size_t)b0 << 20);
    unsigned short* yb = yw + ((size_t)b0 << 20) + ((size_t)J0 << 10);

#pragma unroll 1
    for (int jp = 0; jp < 4; ++jp) {
        const int Jr = J0 + 2 * jp;
        float yv0 = fmaf((float)Jr, SSTEP, -1.0f);
        float yv1 = fmaf((float)(Jr + 1), SSTEP, -1.0f);
        float dy0 = yv0 - y0, dy1 = yv1 - y0;
        float dyt0 = fmaf(dy0, dy0, rc2), dyt1 = fmaf(dy1, dy1, rc2);
        unsigned short* yrow0 = yb + ((2 * jp) << 10);
        unsigned short* yrow1 = yrow0 + 1024;

        float ixa[8], iya[8];
        bool bad = false;
#pragma unroll
        for (int e = 0; e < 8; ++e) {          // e = r*4 + q
            int r = e >> 2, q = e & 3;
            int I = (q << 8) + tid;
            float yv  = r ? yv1 : yv0;
            float dy  = r ? dy1 : dy0;
            float dyt = r ? dyt1 : dyt0;
            float xv = fmaf((float)I, SSTEP, -1.0f);
            float dx = xv - x0;
            float s  = bpar * __builtin_amdgcn_rsqf(fmaf(dx, dx, dyt));
            float gx = xv - dx * s + sub0;
            float gy = yv - dy * s + sub1;
            ixa[e] = (gx + 1.0f) * (0.5f * 1023.0f);
            iya[e] = (gy + 1.0f) * (0.5f * 1023.0f);
            bad |= !(ixa[e] >= 0.f && ixa[e] < 1023.f &&
                     iya[e] >= 0.f && iya[e] < 1023.f);
        }
        if (!__any(bad)) {
            float v00[8], v01[8], v10[8], v11[8], fxs[8], fys[8];
#pragma unroll
            for (int e = 0; e < 8; ++e) {
                float fx = floorf(ixa[e]), fy = floorf(iya[e]);
                fxs[e] = fx; fys[e] = fy;
                const float* p = sb + (((int)fy) << 10) + (int)fx;
                v00[e] = p[0];
                v01[e] = p[1];
                v10[e] = p[WW];
                v11[e] = p[WW + 1];
            }
            __builtin_amdgcn_sched_barrier(0);   // hold all 32 loads in flight
#pragma unroll
            for (int e = 0; e < 8; ++e) {
                float wx1 = ixa[e] - fxs[e];
                float wy1 = iya[e] - fys[e];
                float wx0 = 1.f - wx1;
                float r0 = fmaf(wx1, v01[e], wx0 * v00[e]);
                float r1 = fmaf(wx1, v11[e], wx0 * v10[e]);
                float val = fmaf(wy1, r1, (1.f - wy1) * r0);
                unsigned short* yr = (e >> 2) ? yrow1 : yrow0;
                yr[((e & 3) << 8) + tid] = f2bf(val);
            }
        } else {
#pragma unroll
            for (int e = 0; e < 8; ++e) {
                int I = ((e & 3) << 8) + tid;
                int J = Jr + (e >> 2);
                float val = warp_sample(sb, I, J, bpar, rc2, sub0, sub1, x0, y0);
                unsigned short* yr = (e >> 2) ? yrow1 : yrow0;
                yr[((e & 3) << 8) + tid] = f2bf(val);
            }
        }
    }
}

// ---------------- split kernel 2: stage bf16 tile -> MFMA conv --------------
// Depth-2 A prefetch + ping-pong B prefetch (BfA/BfB): ds_reads for v+2 issue
// right after v's MFMAs (WAR-ordered), completing under v+1's MFMAs.
__global__ __launch_bounds__(256, 4) void conv_kernel(
        const unsigned short* __restrict__ yw, const float* __restrict__ pp,
        float* __restrict__ out) {
    __shared__ unsigned short ThT[HALO_J * PITCH_T];   // [hc][hr'], 30.8KB

    const int tid = threadIdx.x;
    const int j0 = blockIdx.x * TJ;
    const int i0 = blockIdx.y * TI;
    const int b0 = blockIdx.z;

    const int lane = tid & 63;
    const int wv = tid >> 6;
    const int nrow = lane & 31;
    const int khalf = lane >> 5;

    // issue A-loads for v=0,1 BEFORE staging so they land under the barrier
    const short8* Ap = ((const short8*)(pp + AOFF2)) + lane;
    short8 AfA[4], AfB[4];
#pragma unroll
    for (int d = 0; d < 4; ++d) AfA[d] = Ap[d * 64];
#pragma unroll
    for (int d = 0; d < 4; ++d) AfB[d] = Ap[256 + d * 64];

    const unsigned short* wb = yw + ((size_t)b0 << 20);

    // ---- staging: 148 rows x 12 chunks = 1776 16B loads, zero-fill OOB ----
    for (int p = tid; p < HALO_J * 12; p += 256) {
        int hc = (int)((unsigned)p / 12u);
        int c  = p - hc * 12;
        int J  = j0 - 10 + hc;
        int xs = i0 - 16 + c * 8;
        short8 d8 = {0, 0, 0, 0, 0, 0, 0, 0};
        if ((unsigned)J < HH && (unsigned)xs < WW)
            d8 = *(const short8*)&wb[J * WW + xs];
        *(short8*)&ThT[hc * PITCH_T + c * 8] = d8;
    }
    __syncthreads();

    float16 acc[2];
#pragma unroll
    for (int m = 0; m < 2; ++m)
#pragma unroll
        for (int q = 0; q < 16; ++q) acc[m][q] = 0.f;

    const unsigned short* bpbase = &ThT[(32 * wv + nrow) * PITCH_T + khalf * 8];

    short8 BfA[6], BfB[6];
#pragma unroll
    for (int c = 0; c < 6; ++c) BfA[c] = *(const short8*)&bpbase[16 * c];
#pragma unroll
    for (int c = 0; c < 6; ++c) BfB[c] = *(const short8*)&bpbase[PITCH_T + 16 * c];

    // ---- v-loop x2 unrolled: consume (AfA,BfA)/(AfB,BfB); prefetch v+2/v+3 --
#pragma unroll 1
    for (int v = 0; v < 18; v += 2) {
#pragma unroll
        for (int mq = 0; mq < 2; ++mq)
#pragma unroll
            for (int d = 0; d < 4; ++d)
                acc[mq] = __builtin_amdgcn_mfma_f32_32x32x16_bf16(
                    AfA[d], BfA[2 * mq + d], acc[mq], 0, 0, 0);
#pragma unroll
        for (int c = 0; c < 6; ++c)
            BfA[c] = *(const short8*)&bpbase[(v + 2) * PITCH_T + 16 * c];
#pragma unroll
        for (int d = 0; d < 4; ++d) AfA[d] = Ap[(v + 2) * 256 + d * 64];

#pragma unroll
        for (int mq = 0; mq < 2; ++mq)
#pragma unroll
            for (int d = 0; d < 4; ++d)
                acc[mq] = __builtin_amdgcn_mfma_f32_32x32x16_bf16(
                    AfB[d], BfB[2 * mq + d], acc[mq], 0, 0, 0);
#pragma unroll
        for (int c = 0; c < 6; ++c)
            BfB[c] = *(const short8*)&bpbase[(v + 3) * PITCH_T + 16 * c];
#pragma unroll
        for (int d = 0; d < 4; ++d) AfB[d] = Ap[(v + 3) * 256 + d * 64];
    }
    // epilogue: v=18 (A-bufs), load v=20 into A-bufs, v=19 (B-bufs), v=20
#pragma unroll
    for (int mq = 0; mq < 2; ++mq)
#pragma unroll
        for (int d = 0; d < 4; ++d)
            acc[mq] = __builtin_amdgcn_mfma_f32_32x32x16_bf16(
                AfA[d], BfA[2 * mq + d], acc[mq], 0, 0, 0);
#pragma unroll
    for (int c = 0; c < 6; ++c)
        BfA[c] = *(const short8*)&bpbase[20 * PITCH_T + 16 * c];
#pragma unroll
    for (int d = 0; d < 4; ++d) AfA[d] = Ap[20 * 256 + d * 64];
#pragma unroll
    for (int mq = 0; mq < 2; ++mq)
#pragma unroll
        for (int d = 0; d < 4; ++d)
            acc[mq] = __builtin_amdgcn_mfma_f32_32x32x16_bf16(
                AfB[d], BfB[2 * mq + d], acc[mq], 0, 0, 0);
#pragma unroll
    for (int mq = 0; mq < 2; ++mq)
#pragma unroll
        for (int d = 0; d < 4; ++d)
            acc[mq] = __builtin_amdgcn_mfma_f32_32x32x16_bf16(
                AfA[d], BfA[2 * mq + d], acc[mq], 0, 0, 0);

    float* ob = out + (size_t)b0 * (WW * (size_t)HH);
    const int gj = j0 + 32 * wv + nrow;
#pragma unroll
    for (int mq = 0; mq < 2; ++mq) {
#pragma unroll
        for (int reg = 0; reg < 16; ++reg) {
            int row = (reg & 3) + 8 * (reg >> 2) + 4 * khalf;
            int gi = i0 + 32 * mq + row;
            ob[(size_t)gi * HH + gj] = acc[mq][reg];
        }
    }
}

// ---------------- fallback: round-4 fused kernel (used if ws too small) ------
__global__ __launch_bounds__(256, 4) void fused_kernel(
        const float* __restrict__ src, const float* __restrict__ pp,
        float* __restrict__ out) {
    __shared__ unsigned short ThT[HALO_J * PITCH_T];

    const int tid = threadIdx.x;
    const int j0 = blockIdx.x * TJ;
    const int i0 = blockIdx.y * TI;
    const int b0 = blockIdx.z;

    const float bpar = pp[441], rc2 = pp[442];
    const float sub0 = pp[443], sub1 = pp[444];
    const float x0 = pp[445], y0 = pp[446];

    const float* sb = src + (size_t)b0 * (HH * (size_t)WW);

    const int NELEM = HALO_J * FILL_I;
#pragma unroll 1
    for (int base = 0; base < NELEM; base += 1024) {
        float vals[4];
        int offs[4];
#pragma unroll
        for (int e = 0; e < 4; ++e) {
            int n = base + (e << 8) + tid;
            float val = 0.f;
            int off = -1;
            if (n < NELEM) {
                int hc = (int)((unsigned)n / 96u);
                int hr = n - hc * 96;
                off = hc * PITCH_T + hr;
                int J = j0 - 10 + hc;
                int I = i0 - 10 + hr;
                if (hr < VALID_I && (unsigned)J < HH && (unsigned)I < WW)
                    val = warp_sample(sb, I, J, bpar, rc2, sub0, sub1, x0, y0);
            }
            vals[e] = val;
            offs[e] = off;
        }
#pragma unroll
        for (int e = 0; e < 4; ++e) {
            if (offs[e] >= 0) ThT[offs[e]] = f2bf(vals[e]);
        }
    }
    __syncthreads();

    const int lane = tid & 63;
    const int wv = tid >> 6;
    const int nrow = lane & 31;
    const int khalf = lane >> 5;

    float16 acc[2];
#pragma unroll
    for (int m = 0; m < 2; ++m)
#pragma unroll
        for (int q = 0; q < 16; ++q) acc[m][q] = 0.f;

    const short8* Aall = (const short8*)(pp + AOFF);

#pragma unroll 1
    for (int v = 0; v < 21; ++v) {
        short8 Af[4];
#pragma unroll
        for (int d = 0; d < 4; ++d)
            Af[d] = Aall[(v * 4 + d) * 64 + lane];

        const unsigned short* bp = &ThT[(32 * wv + nrow + v) * PITCH_T + khalf * 8];
        short8 Bf[6];
#pragma unroll
        for (int c = 0; c < 6; ++c)
            Bf[c] = *(const short8*)&bp[16 * c];

#pragma unroll
        for (int mq = 0; mq < 2; ++mq) {
#pragma unroll
            for (int d = 0; d < 4; ++d)
                acc[mq] = __builtin_amdgcn_mfma_f32_32x32x16_bf16(
                    Af[d], Bf[2 * mq + d], acc[mq], 0, 0, 0);
        }
    }

    float* ob = out + (size_t)b0 * (WW * (size_t)HH);
    const int gj = j0 + 32 * wv + nrow;
#pragma unroll
    for (int mq = 0; mq < 2; ++mq) {
#pragma unroll
        for (int reg = 0; reg < 16; ++reg) {
            int row = (reg & 3) + 8 * (reg >> 2) + 4 * khalf;
            int gi = i0 + 32 * mq + row;
            ob[(size_t)gi * HH + gj] = acc[mq][reg];
        }
    }
}

extern "C" void kernel_launch(void* const* d_in, const int* in_sizes, int n_in,
                              void* d_out, int out_size, void* d_ws, size_t ws_size,
                              hipStream_t stream) {
    const float* src     = (const float*)d_in[0];
    const float* raw_psf = (const float*)d_in[1];
    const float* x0      = (const float*)d_in[2];
    const float* y0      = (const float*)d_in[3];
    const float* raw_b   = (const float*)d_in[4];
    const float* raw_rc  = (const float*)d_in[5];
    const float* raw_sub = (const float*)d_in[6];
    float* ws = (float*)d_ws;

    prep_kernel<<<1, 512, 0, stream>>>(raw_psf, x0, y0, raw_b, raw_rc, raw_sub, ws);

    dim3 grid(HH / TJ, WW / TI, 16);   // (8, 16, 16) = 2048 blocks
    if (ws_size >= (size_t)NEED_WS) {
        unsigned short* yw = (unsigned short*)(ws + YOFF);
        warp_kernel<<<2048, 256, 0, stream>>>(src, ws, yw);
        conv_kernel<<<grid, 256, 0, stream>>>(yw, ws, (float*)d_out);
    } else {
        fused_kernel<<<grid, 256, 0, stream>>>(src, ws, (float*)d_out);
    }
}